// Round 5
// baseline (1138.172 us; speedup 1.0000x reference)
//
#include <hip/hip_runtime.h>

// ---------------------------------------------------------------------------
// CasualGraph on MI355X. 3 layers of source = T^T (T x); x = LN(source+x0);
// then per-hyperedge mean of final pre-norm source, global max over edges.
// bf16 MFMA 16x16x32, fp32 accumulate, split-K=8 (final GEMM 16).
//
// KEY IDEA (R5): all GEMM operands live in a PACKED TILE layout --
//   32-KB tiles of [256 rows][64 k], tiles ordered (n>>8, k>>6), with the
//   LDS XOR bank-swizzle pre-baked into the 16-B chunk position. Every GEMM
//   block then reads two contiguous 512-KB streams (fully sequential DRAM),
//   vs the 16-KB-strided 128-B slivers of R1-R4 that capped ingest at
//   ~2-4 TB/s. Staging via global_load_lds (lane-linear LDS scatter).
// ---------------------------------------------------------------------------

typedef __bf16 bf16;
typedef __bf16 bf16x8 __attribute__((ext_vector_type(8)));
typedef float f32x4 __attribute__((ext_vector_type(4)));

// element index into packed layout; Kch = K/64 of this matrix
__device__ __forceinline__ size_t packIdx(int n, int k, int Kch) {
  return ((size_t)(n >> 8) * Kch + (k >> 6)) * 16384 + (size_t)(n & 255) * 64 +
         ((((k >> 3) & 7) ^ (n & 7)) << 3) + (k & 7);
}

__device__ __forceinline__ void gld_lds16(const bf16* g, bf16* l) {
  __builtin_amdgcn_global_load_lds(
      (const __attribute__((address_space(1))) unsigned int*)g,
      (__attribute__((address_space(3))) unsigned int*)l, 16, 0, 0);
}

// ---------------------------------------------------------------------------
// P[z][m][n] = sum_{k in split z} A[m][k]*B[n][k].  A,B packed bf16.
// BM=256(=M), BN=256, BK=64. 512 threads = 8 waves (2x4), wave tile 128x64.
// Depth-2 DMA pipeline, s_waitcnt vmcnt(8) (full drain only on last iter).
// ---------------------------------------------------------------------------
__global__ __launch_bounds__(512) void gemm_packed(const bf16* __restrict__ Ap,
                                                   const bf16* __restrict__ Bp,
                                                   float* __restrict__ P,
                                                   int N, int Kch, int Ks) {
  constexpr int TM = 8, TN = 4;
  __shared__ __align__(16) bf16 As[2][256 * 64];  // 32 KB each
  __shared__ __align__(16) bf16 Bs[2][256 * 64];  // 32 KB each

  const int t = threadIdx.x, w = t >> 6, l = t & 63;
  const int n0 = blockIdx.x * 256;
  const int kb0 = (blockIdx.z * Ks) >> 6;

  // per-lane packed source pointers: tile-linear, lane reads 16 B at 16*l
  const bf16* pA = Ap + (size_t)kb0 * 16384 + w * 512 + l * 8;
  const bf16* pB =
      Bp + ((size_t)(n0 >> 8) * Kch + kb0) * 16384 + w * 512 + l * 8;

  auto stage = [&](int kk, int buf) {
    const size_t ko = (size_t)kk * 16384;
#pragma unroll
    for (int q = 0; q < 4; ++q)
      gld_lds16(pA + ko + q * 4096, &As[buf][(q * 64 + w * 8) * 64]);
#pragma unroll
    for (int q = 0; q < 4; ++q)
      gld_lds16(pB + ko + q * 4096, &Bs[buf][(q * 64 + w * 8) * 64]);
  };

  const int lm = l & 15, kq = l >> 4;
  const int wm = (w >> 2) * 128;  // 2 wave-rows
  const int wn = (w & 3) * 64;    // 4 wave-cols

  f32x4 acc[TM][TN] = {};
  const int nk = Ks >> 6;

  stage(0, 0);
  stage(1, 1);

  for (int kk = 0; kk < nk; ++kk) {
    const int buf = kk & 1;
    if (kk + 1 < nk)
      asm volatile("s_waitcnt vmcnt(8)" ::: "memory");
    else
      asm volatile("s_waitcnt vmcnt(0)" ::: "memory");
    asm volatile("s_barrier" ::: "memory");

#pragma unroll
    for (int ks = 0; ks < 2; ++ks) {
      bf16x8 af[TM], bfr[TN];
#pragma unroll
      for (int i = 0; i < TM; ++i) {
        const int r = wm + i * 16 + lm;
        const int c = ((ks * 4 + kq) ^ (r & 7)) * 8;
        af[i] = *(const bf16x8*)(&As[buf][r * 64 + c]);
      }
#pragma unroll
      for (int j = 0; j < TN; ++j) {
        const int r = wn + j * 16 + lm;
        const int c = ((ks * 4 + kq) ^ (r & 7)) * 8;
        bfr[j] = *(const bf16x8*)(&Bs[buf][r * 64 + c]);
      }
#pragma unroll
      for (int i = 0; i < TM; ++i)
#pragma unroll
        for (int j = 0; j < TN; ++j)
          acc[i][j] = __builtin_amdgcn_mfma_f32_16x16x32_bf16(af[i], bfr[j],
                                                              acc[i][j], 0, 0, 0);
    }
    asm volatile("s_barrier" ::: "memory");
    if (kk + 2 < nk) stage(kk + 2, buf);
  }

  // epilogue: C/D layout col = lane&15, row = kq*4 + r
  float* Pz = P + (size_t)blockIdx.z * 256 * N;
#pragma unroll
  for (int i = 0; i < TM; ++i) {
    const int mrow = wm + i * 16 + kq * 4;
#pragma unroll
    for (int j = 0; j < TN; ++j) {
      const int col = n0 + wn + j * 16 + lm;
#pragma unroll
      for (int r = 0; r < 4; ++r)
        Pz[(size_t)(mrow + r) * N + col] = acc[i][j][r];
    }
  }
}

// ---------------------------------------------------------------------------
// out_packed(d, k) = bf16( sum_{z<S} P[z][d][k] );  P plain [256][Nk] rows.
// ---------------------------------------------------------------------------
template <int S>
__global__ __launch_bounds__(256) void reduceS_pack(const float* __restrict__ P,
                                                    bf16* __restrict__ out,
                                                    size_t MN) {
  const size_t i4 = ((size_t)blockIdx.x * 256 + threadIdx.x) * 4;
  if (i4 >= MN) return;
  f32x4 a = *(const f32x4*)(P + i4);
#pragma unroll
  for (int z = 1; z < S; ++z) a = a + *(const f32x4*)(P + (size_t)z * MN + i4);
  bf16 o[4] = {(bf16)a[0], (bf16)a[1], (bf16)a[2], (bf16)a[3]};
  const int d = (int)(i4 >> 13), k = (int)(i4 & 8191);
  *(int2*)(out + packIdx(d, k, 128)) = *(const int2*)o;
}

// ---------------------------------------------------------------------------
// 64x64 tile transpose/convert: src [R][C] f32 ->
//   cpyP: packed bf16 copy  [R rows][C k]   (Kch = C/64)
//   trbP: packed bf16 transpose [C rows][R k] (Kch = R/64)
//   trf : plain f32 transpose [C][R]
// ---------------------------------------------------------------------------
__global__ __launch_bounds__(256) void transpose_conv(
    const float* __restrict__ src, int R, int C, bf16* __restrict__ cpyP,
    bf16* __restrict__ trbP, float* __restrict__ trf) {
  __shared__ float tile[64][65];
  const int t = threadIdx.x;
  const int col = t & 63, rb4 = t >> 6;
  const int r0 = blockIdx.y * 64, c0 = blockIdx.x * 64;
  const int KchC = C >> 6, KchR = R >> 6;
#pragma unroll
  for (int rr = 0; rr < 64; rr += 4) {
    const int row = rr + rb4;
    const float v = src[(size_t)(r0 + row) * C + c0 + col];
    tile[row][col] = v;
    if (cpyP) cpyP[packIdx(r0 + row, c0 + col, KchC)] = (bf16)v;
  }
  __syncthreads();
#pragma unroll
  for (int rr = 0; rr < 64; rr += 4) {
    const int row = rr + rb4;
    const float v = tile[col][row];  // = src[r0+col][c0+row]
    if (trbP) trbP[packIdx(c0 + row, r0 + col, KchR)] = (bf16)v;
    if (trf) trf[(size_t)(c0 + row) * R + r0 + col] = v;
  }
}

// ---------------------------------------------------------------------------
// LayerNorm over d, fused 8-way split-K reduce; writes Xt PACKED.
// block (32 nodes, 8 d-groups)
// ---------------------------------------------------------------------------
__global__ __launch_bounds__(256) void ln_kernel(const float* __restrict__ P,
                                                 const float* __restrict__ x0t,
                                                 const float* __restrict__ gamma,
                                                 const float* __restrict__ beta,
                                                 bf16* __restrict__ Xt) {
  constexpr size_t MN = (size_t)256 * 8192;
  const int tx = threadIdx.x;
  const int ty = threadIdx.y;
  const int i = blockIdx.x * 32 + tx;
  float vbuf[32];
  float s = 0.f, s2 = 0.f;
#pragma unroll
  for (int dd = 0; dd < 32; ++dd) {
    const int d = ty * 32 + dd;
    const size_t idx = (size_t)d * 8192 + i;
    float v = x0t[idx];
#pragma unroll
    for (int z = 0; z < 8; ++z) v += P[(size_t)z * MN + idx];
    vbuf[dd] = v;
    s += v;
    s2 += v * v;
  }
  __shared__ float S[8][32], Q[8][32];
  S[ty][tx] = s;
  Q[ty][tx] = s2;
  __syncthreads();
  __shared__ float MU[32], RS[32];
  if (ty == 0) {
    float a = 0.f, b = 0.f;
#pragma unroll
    for (int r = 0; r < 8; ++r) {
      a += S[r][tx];
      b += Q[r][tx];
    }
    const float mu = a * (1.0f / 256.0f);
    const float var = b * (1.0f / 256.0f) - mu * mu;
    MU[tx] = mu;
    RS[tx] = rsqrtf(var + 1e-5f);
  }
  __syncthreads();
  const float mu = MU[tx], rs = RS[tx];
#pragma unroll
  for (int dd = 0; dd < 32; ++dd) {
    const int d = ty * 32 + dd;
    const float y = (vbuf[dd] - mu) * rs * gamma[d] + beta[d];
    Xt[packIdx(d, i, 128)] = (bf16)y;
  }
}

// ---------------------------------------------------------------------------
// counts: cnt[e] += partial column sums of H (fp32, coalesced over e)
// ---------------------------------------------------------------------------
__global__ __launch_bounds__(256) void counts_from_H(const float* __restrict__ H,
                                                     float* __restrict__ cnt) {
  const int e = blockIdx.x * 256 + threadIdx.x;
  const int i0 = blockIdx.y * 1024;
  float s = 0.f;
  for (int i = i0; i < i0 + 1024; ++i) s += H[(size_t)i * 4096 + e];
  atomicAdd(&cnt[e], s);
}

__global__ __launch_bounds__(256) void invert_kernel(const float* __restrict__ cnt,
                                                     float* __restrict__ invc) {
  const int e = blockIdx.x * 256 + threadIdx.x;
  invc[e] = 1.0f / cnt[e];
}

// ---------------------------------------------------------------------------
// out[d] = max_e (sum_{z<S} P[z][d][e]) * invc[e]
// ---------------------------------------------------------------------------
__global__ __launch_bounds__(256) void final_max(const float* __restrict__ P,
                                                 const float* __restrict__ invc,
                                                 float* __restrict__ out,
                                                 int S) {
  constexpr size_t MN = (size_t)256 * 4096;
  const int d = blockIdx.x;
  float m = -3.4e38f;
  for (int e = threadIdx.x; e < 4096; e += 256) {
    const size_t idx = (size_t)d * 4096 + e;
    float s = 0.f;
    for (int z = 0; z < S; ++z) s += P[z * MN + idx];
    m = fmaxf(m, s * invc[e]);
  }
  __shared__ float red[256];
  red[threadIdx.x] = m;
  __syncthreads();
  for (int k = 128; k > 0; k >>= 1) {
    if (threadIdx.x < k)
      red[threadIdx.x] = fmaxf(red[threadIdx.x], red[threadIdx.x + k]);
    __syncthreads();
  }
  if (threadIdx.x == 0) out[d] = red[0];
}

// ---------------------------------------------------------------------------
extern "C" void kernel_launch(void* const* d_in, const int* in_sizes, int n_in,
                              void* d_out, int out_size, void* d_ws,
                              size_t ws_size, hipStream_t stream) {
  const float* x0 = (const float*)d_in[0];    // [8192][256]
  const float* T = (const float*)d_in[1];     // [8192][8192]
  const float* H = (const float*)d_in[2];     // [8192][4096]
  const float* gamma = (const float*)d_in[3]; // [256]
  const float* beta = (const float*)d_in[4];  // [256]

  constexpr int Nn = 8192, E = 4096, D = 256, K = 8192;
  constexpr int Kch = K / 64;  // 128

  char* w = (char*)d_ws;
  size_t off = 0;
  auto carve = [&](size_t bytes) {
    char* p = w + off;
    off += (bytes + 255) & ~(size_t)255;
    return p;
  };
  bf16* Tb = (bf16*)carve((size_t)Nn * Nn * 2);   // packed
  bf16* Tt = (bf16*)carve((size_t)Nn * Nn * 2);   // packed
  bf16* Htb = (bf16*)carve((size_t)E * Nn * 2);   // packed
  float* x0t = (float*)carve((size_t)D * Nn * 4); // plain [d][i]
  bf16* Xt = (bf16*)carve((size_t)D * Nn * 2);    // packed
  bf16* tt = (bf16*)carve((size_t)D * Nn * 2);    // packed
  bf16* stb = (bf16*)carve((size_t)D * Nn * 2);   // packed
  float* cnt = (float*)carve((size_t)E * 4);
  float* invc = (float*)carve((size_t)E * 4);
  float* P = (float*)carve((size_t)8 * D * Nn * 4);  // 64 MB partials

  if (off > ws_size) {  // workspace too small: fail loudly (out = 0)
    hipMemsetAsync(d_out, 0, (size_t)out_size * 4, stream);
    return;
  }

  // one-time layout prep (packed-tile outputs)
  hipMemsetAsync(cnt, 0, (size_t)E * 4, stream);
  transpose_conv<<<dim3(128, 128), 256, 0, stream>>>(T, Nn, Nn, Tb, Tt, nullptr);
  transpose_conv<<<dim3(64, 128), 256, 0, stream>>>(H, Nn, E, nullptr, Htb, nullptr);
  transpose_conv<<<dim3(4, 128), 256, 0, stream>>>(x0, Nn, D, nullptr, Xt, x0t);
  counts_from_H<<<dim3(16, 8), 256, 0, stream>>>(H, cnt);
  invert_kernel<<<16, 256, 0, stream>>>(cnt, invc);

  const size_t MN = (size_t)D * Nn;
  for (int layer = 0; layer < 3; ++layer) {
    // P = split-K(8) partials of  tt[d][j] = sum_k Xt[d][k] * Tb[j][k]
    gemm_packed<<<dim3(32, 1, 8), 512, 0, stream>>>(Xt, Tb, P, Nn, Kch, K / 8);
    reduceS_pack<8><<<(int)(MN / 1024), 256, 0, stream>>>(P, tt, MN);
    // P = split-K(8) partials of  st[d][i] = sum_j tt[d][j] * Tt[i][j]
    gemm_packed<<<dim3(32, 1, 8), 512, 0, stream>>>(tt, Tt, P, Nn, Kch, K / 8);
    if (layer < 2) {
      ln_kernel<<<dim3(256), dim3(32, 8), 0, stream>>>(P, x0t, gamma, beta, Xt);
    } else {
      reduceS_pack<8><<<(int)(MN / 1024), 256, 0, stream>>>(P, stb, MN);
    }
  }

  // P = split-K(16) partials of  sumsT[d][e] = sum_i stb[d][i] * Htb[e][i]
  gemm_packed<<<dim3(16, 1, 16), 512, 0, stream>>>(stb, Htb, P, E, Kch, K / 16);
  final_max<<<D, 256, 0, stream>>>(P, invc, (float*)d_out, 16);
}